// Round 5
// baseline (207.497 us; speedup 1.0000x reference)
//
#include <hip/hip_runtime.h>

// YOLO loss: N=4096, S=14, B=2, NCLS=20.  Cells = 4096*14*14 = 802816.
//
// v6: v1 verbatim + spread atomics (theory-discriminating probe).
//  - Ladder facts: v1 (direct loads, 49% occ) = 70us; v5 (gload_lds staging,
//    22% occ) = 67us; warm rocprof replays == cold in both -> not HBM-bound,
//    not occupancy-bound.
//  - v3's clean atomic datapoint (31.4K same-line RMWs -> 180us) gives
//    ~13.7cy/RMW line-serialized. v1 issued 12.5K RMWs into ONE 64B line ->
//    ~71us == its whole runtime: v1 was atomic-drain-bound and its memory
//    phase was never observed. v5 fixed atomics but added LDS round-trip +
//    vmcnt(0) drain + barrier at 3 blocks/CU -> its 67us is that structure's
//    memory phase.
//  - v6 isolates: v1's exact main kernel (36 VGPR, 8 waves/SIMD, no staging,
//    no barriers) with ONLY the atomic sink changed: 4 RMWs/block spread over
//    32 cache lines (98/line ~ 0.6us tail, lines parallel across TCC slices).
//  - If this lands 25-45us: atomic theory confirmed, keep pushing structure.
//    If ~67us: ~2.6 TB/s beyond-L2 delivery wall confirmed on compulsory
//    traffic (172MB read-once, no reuse) -> roofline.
//  - Launch count is free (harness overhead fixed ~136us at 2/3/4 launches),
//    so v1's separate detect kernel is kept.

#define NCELLS (4096 * 14 * 14)
#define NBLOCKS (NCELLS / 256)   // 3136, exact
#define NLINES 32                // partial-sum cache lines (32 x 64B = 2KB)

// ws layout (floats): lines j=0..31: ws[16j+k], k=0..3 = cls,noobj,contain,reg
// partials for blocks with (b&31)==j.  int at float-index 512 = mask-mode flag.

__global__ void yolo_zero_kernel(float* __restrict__ ws) {
    const int t = threadIdx.x;   // 256 threads
#pragma unroll
    for (int i = 0; i < 3; ++i) {
        const int k = t + 256 * i;
        if (k < 544) ws[k] = 0.0f;   // 32 lines + flag line
    }
}

// Detect whether the mask buffer is int32 (bytes 4k+1..4k+3 all zero) or
// 1-byte bool (random nonzero bytes at non-multiple-of-4 offsets).
// Scans first 4096 int32 slots = 16 KB (both layouts are larger than that).
__global__ void yolo_detect_kernel(const unsigned char* __restrict__ mb,
                                   int* __restrict__ flag) {
    int t = threadIdx.x;
    unsigned int found = 0;
#pragma unroll
    for (int k = 0; k < 16; ++k) {
        int slot = t * 16 + k;
        found |= mb[4 * slot + 1] | mb[4 * slot + 2] | mb[4 * slot + 3];
    }
    if (found) atomicOr(flag, 1);  // 1 => bool8 layout
}

__global__ __launch_bounds__(256) void yolo_main_kernel(
    const float* __restrict__ pred,
    const float* __restrict__ tbox,
    const float* __restrict__ tcls,
    const void* __restrict__ mask,
    const int* __restrict__ flag,
    float* __restrict__ ws) {
    const int c = blockIdx.x * 256 + threadIdx.x;  // grid covers NCELLS exactly

    // ---- loads (vectorized) ----
    float pv[30];
    {
        const float2* p2 = (const float2*)(pred + (long long)30 * c);  // 120B/cell -> 8B aligned
#pragma unroll
        for (int k = 0; k < 15; ++k) {
            float2 t = p2[k];
            pv[2 * k] = t.x;
            pv[2 * k + 1] = t.y;
        }
    }
    const float4 tb = *(const float4*)(tbox + (long long)4 * c);
    float tc[20];
    {
        const float4* c4 = (const float4*)(tcls + (long long)20 * c);  // 80B/cell -> 16B aligned
#pragma unroll
        for (int k = 0; k < 5; ++k) {
            float4 t = c4[k];
            tc[4 * k] = t.x;
            tc[4 * k + 1] = t.y;
            tc[4 * k + 2] = t.z;
            tc[4 * k + 3] = t.w;
        }
    }
    const int mode = *flag;  // uniform across grid
    float m;
    if (mode) {
        m = ((const unsigned char*)mask)[c] ? 1.0f : 0.0f;
    } else {
        m = ((const int*)mask)[c] ? 1.0f : 0.0f;
    }

    // ---- per-cell losses (bit-identical to v1..v5) ----
    float s = 0.0f;
#pragma unroll
    for (int i = 0; i < 20; ++i) {
        float d = pv[10 + i] - tc[i];
        s += d * d;
    }
    float cls_s = m * s;

    float conf0 = pv[4], conf1 = pv[9];
    float noobj_s = (1.0f - m) * (conf0 * conf0 + conf1 * conf1);

    float iou[2];
    float at = (tb.z - tb.x) * (tb.w - tb.y);
#pragma unroll
    for (int b = 0; b < 2; ++b) {
        int base = 5 * b;
        float x = pv[base] / 14.0f;
        float y = pv[base + 1] / 14.0f;
        float w = pv[base + 2];
        float h = pv[base + 3];
        float p1x = x - w * 0.5f, p1y = y - h * 0.5f;
        float p2x = x + w * 0.5f, p2y = y + h * 0.5f;
        float ltx = fmaxf(p1x, tb.x), lty = fmaxf(p1y, tb.y);
        float rbx = fminf(p2x, tb.z), rby = fminf(p2y, tb.w);
        float iw = fmaxf(rbx - ltx, 0.0f), ih = fmaxf(rby - lty, 0.0f);
        float inter = iw * ih;
        float ap = w * h;
        iou[b] = inter / (ap + at - inter);
    }
    // jnp.argmax: first max wins -> pick box1 only if strictly greater
    int best = (iou[1] > iou[0]) ? 5 : 0;
    float bx = pv[best], by = pv[best + 1], bw = pv[best + 2], bh = pv[best + 3],
          bc = pv[best + 4];

    float contain_s = m * (bc - 1.0f) * (bc - 1.0f);

    float dx = bx - tb.x, dy = by - tb.y;
    float dw = sqrtf(bw) - sqrtf(tb.z);
    float dh = sqrtf(bh) - sqrtf(tb.w);
    float reg_s = m * (dx * dx + dy * dy + dw * dw + dh * dh);

    // ---- reduction: wave64 shuffle -> LDS -> 4 atomics per block ----
#pragma unroll
    for (int off = 32; off > 0; off >>= 1) {
        cls_s += __shfl_down(cls_s, off, 64);
        noobj_s += __shfl_down(noobj_s, off, 64);
        contain_s += __shfl_down(contain_s, off, 64);
        reg_s += __shfl_down(reg_s, off, 64);
    }
    __shared__ float red[4][4];
    int lane = threadIdx.x & 63;
    int wid = threadIdx.x >> 6;
    if (lane == 0) {
        red[wid][0] = cls_s;
        red[wid][1] = noobj_s;
        red[wid][2] = contain_s;
        red[wid][3] = reg_s;
    }
    __syncthreads();
    if (threadIdx.x < 4) {
        float v = red[0][threadIdx.x] + red[1][threadIdx.x] +
                  red[2][threadIdx.x] + red[3][threadIdx.x];
        // spread over 32 cache lines: ~98 line-serialized RMWs per line
        atomicAdd(&ws[16 * (blockIdx.x & (NLINES - 1)) + threadIdx.x], v);
    }
}

__global__ void yolo_final_kernel(const float* __restrict__ ws,
                                  float* __restrict__ out) {
    const int t = threadIdx.x;   // 64 threads; lines 0..31 carry data
    float4 v = make_float4(0.f, 0.f, 0.f, 0.f);
    if (t < NLINES) v = ((const float4*)ws)[4 * t];   // line t: ws[16t..16t+3]
#pragma unroll
    for (int off = 32; off > 0; off >>= 1) {
        v.x += __shfl_down(v.x, off, 64);
        v.y += __shfl_down(v.y, off, 64);
        v.z += __shfl_down(v.z, off, 64);
        v.w += __shfl_down(v.w, off, 64);
    }
    if (t == 0) {
        const float inv_n = 1.0f / 4096.0f;
        const float cls = v.x * inv_n;
        const float noobj = v.y * inv_n;
        const float contain = v.z * inv_n;
        const float reg = v.w * inv_n;
        out[0] = cls + 0.5f * noobj + 5.0f * reg + contain;
        out[1] = reg;
        out[2] = contain;
        out[3] = noobj;
        out[4] = cls;
    }
}

extern "C" void kernel_launch(void* const* d_in, const int* in_sizes, int n_in,
                              void* d_out, int out_size, void* d_ws,
                              size_t ws_size, hipStream_t stream) {
    const float* pred = (const float*)d_in[0];
    const float* tbox = (const float*)d_in[1];
    const float* tcls = (const float*)d_in[2];
    const void* mask = d_in[3];
    float* ws = (float*)d_ws;
    float* out = (float*)d_out;

    yolo_zero_kernel<<<1, 256, 0, stream>>>(ws);
    yolo_detect_kernel<<<1, 256, 0, stream>>>((const unsigned char*)mask,
                                              (int*)(ws + 512));
    yolo_main_kernel<<<NBLOCKS, 256, 0, stream>>>(pred, tbox, tcls, mask,
                                                  (const int*)(ws + 512), ws);
    yolo_final_kernel<<<1, 64, 0, stream>>>(ws, out);
}